// Round 1
// baseline (1092.907 us; speedup 1.0000x reference)
//
#include <hip/hip_runtime.h>

#define SS 1024
#define DD 512
#define BATCH 8
#define MIN_T 0.1f
#define MAX_T 0.9f

constexpr int BM = 64, BN = 64, BK = 16;
constexpr int LDSP = 4;  // pad: keeps 16B alignment (68 floats = 272B rows) and <=2-way conflicts

// ---------------- denominators ----------------
__global__ void denom_row_k(const float* __restrict__ adj, float* __restrict__ rden) {
    int row = blockIdx.x;  // b*S + x
    const float* a = adj + (size_t)row * SS;
    float s = 0.f;
    for (int y = threadIdx.x; y < SS; y += blockDim.x) {
        float v = a[y];
        s += (v >= MIN_T && v <= MAX_T) ? v : 0.f;
    }
    __shared__ float red[256];
    red[threadIdx.x] = s;
    __syncthreads();
    for (int off = 128; off > 0; off >>= 1) {
        if (threadIdx.x < off) red[threadIdx.x] += red[threadIdx.x + off];
        __syncthreads();
    }
    if (threadIdx.x == 0) rden[row] = 1.0f / (red[0] + 1.0f);
}

__global__ void denom_col_k(const float* __restrict__ adj, float* __restrict__ rden) {
    int b = blockIdx.y;
    int y = blockIdx.x * 256 + threadIdx.x;
    const float* a = adj + (size_t)b * SS * SS;
    float s = 0.f;
    for (int x = 0; x < SS; ++x) {
        float v = a[(size_t)x * SS + y];
        s += (v >= MIN_T && v <= MAX_T) ? v : 0.f;
    }
    rden[b * SS + y] = 1.0f / (s + 1.0f);
}

// ---------------- Y = prunedA . X + X  (per batch S x S times S x D) ----------------
template <bool TRANS>
__global__ void agg_k(const float* __restrict__ adj, const float* __restrict__ X,
                      float* __restrict__ Y) {
    __shared__ float As[BK][BM + LDSP];
    __shared__ float Bs[BK][BN + LDSP];
    int b = blockIdx.z;
    int m0 = blockIdx.x * BM, n0 = blockIdx.y * BN;
    const float* A = adj + (size_t)b * SS * SS;
    const float* Xb = X + (size_t)b * SS * DD;
    int tid = threadIdx.x;
    int tx = tid & 15, ty = tid >> 4;
    float acc[4][4] = {};

    for (int k0 = 0; k0 < SS; k0 += BK) {
        if (!TRANS) {
#pragma unroll
            for (int p = 0; p < 4; ++p) {
                int m = (tid >> 4) + p * 16, k = tid & 15;
                float v = A[(size_t)(m0 + m) * SS + (k0 + k)];
                As[k][m] = (v >= MIN_T && v <= MAX_T) ? v : 0.f;
            }
        } else {
#pragma unroll
            for (int p = 0; p < 4; ++p) {
                int m = tid & 63, k = (tid >> 6) + p * 4;
                float v = A[(size_t)(k0 + k) * SS + (m0 + m)];
                As[k][m] = (v >= MIN_T && v <= MAX_T) ? v : 0.f;
            }
        }
#pragma unroll
        for (int p = 0; p < 4; ++p) {
            int n = tid & 63, k = (tid >> 6) + p * 4;
            Bs[k][n] = Xb[(size_t)(k0 + k) * DD + (n0 + n)];
        }
        __syncthreads();
#pragma unroll
        for (int k = 0; k < BK; ++k) {
            float4 a4 = *(const float4*)&As[k][ty * 4];
            float4 b4 = *(const float4*)&Bs[k][tx * 4];
            float av[4] = {a4.x, a4.y, a4.z, a4.w};
            float bv[4] = {b4.x, b4.y, b4.z, b4.w};
#pragma unroll
            for (int i = 0; i < 4; ++i)
#pragma unroll
                for (int j = 0; j < 4; ++j) acc[i][j] += av[i] * bv[j];
        }
        __syncthreads();
    }
#pragma unroll
    for (int i = 0; i < 4; ++i) {
        int m = m0 + ty * 4 + i;
#pragma unroll
        for (int j = 0; j < 4; ++j) {
            int n = n0 + tx * 4 + j;
            Y[((size_t)b * SS + m) * DD + n] = acc[i][j] + Xb[(size_t)m * DD + n];
        }
    }
}

// ---------------- x' = relu((Y . W + bias) * rden)  (M=B*S, K=D, N=D) ----------------
__global__ void wmm_k(const float* __restrict__ Y, const float* __restrict__ W,
                      const float* __restrict__ bias, const float* __restrict__ rden,
                      float* __restrict__ Xo) {
    __shared__ float As[BK][BM + LDSP];
    __shared__ float Bs[BK][BN + LDSP];
    int m0 = blockIdx.x * BM, n0 = blockIdx.y * BN;
    int tid = threadIdx.x;
    int tx = tid & 15, ty = tid >> 4;
    float acc[4][4] = {};

    for (int k0 = 0; k0 < DD; k0 += BK) {
#pragma unroll
        for (int p = 0; p < 4; ++p) {
            int m = (tid >> 4) + p * 16, k = tid & 15;
            As[k][m] = Y[(size_t)(m0 + m) * DD + (k0 + k)];
        }
#pragma unroll
        for (int p = 0; p < 4; ++p) {
            int n = tid & 63, k = (tid >> 6) + p * 4;
            Bs[k][n] = W[(size_t)(k0 + k) * DD + (n0 + n)];
        }
        __syncthreads();
#pragma unroll
        for (int k = 0; k < BK; ++k) {
            float4 a4 = *(const float4*)&As[k][ty * 4];
            float4 b4 = *(const float4*)&Bs[k][tx * 4];
            float av[4] = {a4.x, a4.y, a4.z, a4.w};
            float bv[4] = {b4.x, b4.y, b4.z, b4.w};
#pragma unroll
            for (int i = 0; i < 4; ++i)
#pragma unroll
                for (int j = 0; j < 4; ++j) acc[i][j] += av[i] * bv[j];
        }
        __syncthreads();
    }
#pragma unroll
    for (int i = 0; i < 4; ++i) {
        int m = m0 + ty * 4 + i;
        float r = rden[m];
#pragma unroll
        for (int j = 0; j < 4; ++j) {
            int n = n0 + tx * 4 + j;
            float h = (acc[i][j] + bias[n]) * r;
            Xo[(size_t)m * DD + n] = h > 0.f ? h : 0.f;
        }
    }
}

// ---------------- t1 = [h1 | 1] . U  (M=B*S, K=513, N=513) ----------------
__global__ void t1_k(const float* __restrict__ h1, const float* __restrict__ U,
                     float* __restrict__ t1) {
    __shared__ float As[BK][BM + LDSP];
    __shared__ float Bs[BK][BN + LDSP];
    int m0 = blockIdx.x * BM, n0 = blockIdx.y * BN;
    int tid = threadIdx.x;
    int tx = tid & 15, ty = tid >> 4;
    float acc[4][4] = {};

    for (int k0 = 0; k0 < 513; k0 += BK) {
#pragma unroll
        for (int p = 0; p < 4; ++p) {
            int m = (tid >> 4) + p * 16, k = tid & 15;
            int kk = k0 + k;
            float v = 0.f;
            if (kk < 512) v = h1[(size_t)(m0 + m) * DD + kk];
            else if (kk == 512) v = 1.0f;
            As[k][m] = v;
        }
#pragma unroll
        for (int p = 0; p < 4; ++p) {
            int n = tid & 63, k = (tid >> 6) + p * 4;
            int kk = k0 + k, nn = n0 + n;
            Bs[k][n] = (kk < 513 && nn < 513) ? U[(size_t)kk * 513 + nn] : 0.f;
        }
        __syncthreads();
#pragma unroll
        for (int k = 0; k < BK; ++k) {
            float4 a4 = *(const float4*)&As[k][ty * 4];
            float4 b4 = *(const float4*)&Bs[k][tx * 4];
            float av[4] = {a4.x, a4.y, a4.z, a4.w};
            float bv[4] = {b4.x, b4.y, b4.z, b4.w};
#pragma unroll
            for (int i = 0; i < 4; ++i)
#pragma unroll
                for (int j = 0; j < 4; ++j) acc[i][j] += av[i] * bv[j];
        }
        __syncthreads();
    }
#pragma unroll
    for (int i = 0; i < 4; ++i) {
        int m = m0 + ty * 4 + i;
#pragma unroll
        for (int j = 0; j < 4; ++j) {
            int nn = n0 + tx * 4 + j;
            if (nn < 513) t1[(size_t)m * 513 + nn] = acc[i][j];
        }
    }
}

// ---------------- out[b,x,y] = t1[b,x,:] . [h2|1][b,y,:]  (per batch M=N=S, K=513) ----------------
__global__ void score_k(const float* __restrict__ t1, const float* __restrict__ h2,
                        float* __restrict__ out) {
    __shared__ float As[BK][BM + LDSP];
    __shared__ float Bs[BK][BN + LDSP];
    int b = blockIdx.z;
    int m0 = blockIdx.x * BM, n0 = blockIdx.y * BN;
    const float* T = t1 + (size_t)b * SS * 513;
    const float* H = h2 + (size_t)b * SS * DD;
    int tid = threadIdx.x;
    int tx = tid & 15, ty = tid >> 4;
    float acc[4][4] = {};

    for (int k0 = 0; k0 < 513; k0 += BK) {
#pragma unroll
        for (int p = 0; p < 4; ++p) {
            int m = (tid >> 4) + p * 16, k = tid & 15;
            int kk = k0 + k;
            As[k][m] = (kk < 513) ? T[(size_t)(m0 + m) * 513 + kk] : 0.f;
        }
#pragma unroll
        for (int p = 0; p < 4; ++p) {
            int n = (tid >> 4) + p * 16, k = tid & 15;
            int kk = k0 + k;
            float v = 0.f;
            if (kk < 512) v = H[(size_t)(n0 + n) * DD + kk];
            else if (kk == 512) v = 1.0f;
            Bs[k][n] = v;
        }
        __syncthreads();
#pragma unroll
        for (int k = 0; k < BK; ++k) {
            float4 a4 = *(const float4*)&As[k][ty * 4];
            float4 b4 = *(const float4*)&Bs[k][tx * 4];
            float av[4] = {a4.x, a4.y, a4.z, a4.w};
            float bv[4] = {b4.x, b4.y, b4.z, b4.w};
#pragma unroll
            for (int i = 0; i < 4; ++i)
#pragma unroll
                for (int j = 0; j < 4; ++j) acc[i][j] += av[i] * bv[j];
        }
        __syncthreads();
    }
#pragma unroll
    for (int i = 0; i < 4; ++i) {
        int m = m0 + ty * 4 + i;
#pragma unroll
        for (int j = 0; j < 4; ++j) {
            int n = n0 + tx * 4 + j;
            out[((size_t)b * SS + m) * SS + n] = acc[i][j];
        }
    }
}

extern "C" void kernel_launch(void* const* d_in, const int* in_sizes, int n_in,
                              void* d_out, int out_size, void* d_ws, size_t ws_size,
                              hipStream_t stream) {
    const float* x0  = (const float*)d_in[0];  // [B,S,D]
    const float* adj = (const float*)d_in[1];  // [B,S,S]
    const float* W1  = (const float*)d_in[2];  // [L,D,D]
    const float* b1  = (const float*)d_in[3];  // [L,D]
    const float* W2  = (const float*)d_in[4];
    const float* b2  = (const float*)d_in[5];
    const float* U   = (const float*)d_in[6];  // [1,513,513]
    float* out = (float*)d_out;

    char* ws = (char*)d_ws;
    const size_t SZ = (size_t)BATCH * SS * DD * sizeof(float);  // 16 MB
    float* h1    = (float*)(ws);
    float* h2    = (float*)(ws + SZ);
    float* bufA  = (float*)(ws + 2 * SZ);
    float* bufY  = (float*)(ws + 3 * SZ);
    float* rden1 = (float*)(ws + 4 * SZ);
    float* rden2 = (float*)(ws + 4 * SZ + BATCH * SS * sizeof(float));
    float* t1    = bufA;  // aliases bufA(+ a bit of bufY), free after GCN phase

    denom_row_k<<<BATCH * SS, 256, 0, stream>>>(adj, rden1);
    denom_col_k<<<dim3(SS / 256, BATCH), 256, 0, stream>>>(adj, rden2);

    dim3 gAgg(SS / BM, DD / BN, BATCH);
    dim3 gW(BATCH * SS / BM, DD / BN);

    // stream 1: forward adjacency
    agg_k<false><<<gAgg, 256, 0, stream>>>(adj, x0, bufY);
    wmm_k<<<gW, 256, 0, stream>>>(bufY, W1, b1, rden1, bufA);
    agg_k<false><<<gAgg, 256, 0, stream>>>(adj, bufA, bufY);
    wmm_k<<<gW, 256, 0, stream>>>(bufY, W1 + DD * DD, b1 + DD, rden1, h1);

    // stream 2: transposed adjacency
    agg_k<true><<<gAgg, 256, 0, stream>>>(adj, x0, bufY);
    wmm_k<<<gW, 256, 0, stream>>>(bufY, W2, b2, rden2, bufA);
    agg_k<true><<<gAgg, 256, 0, stream>>>(adj, bufA, bufY);
    wmm_k<<<gW, 256, 0, stream>>>(bufY, W2 + DD * DD, b2 + DD, rden2, h2);

    // biaffine scoring
    t1_k<<<dim3(BATCH * SS / BM, 9), 256, 0, stream>>>(h1, U, t1);
    score_k<<<dim3(SS / BM, SS / BN, BATCH), 256, 0, stream>>>(t1, h2, out);
}

// Round 2
// 321.749 us; speedup vs baseline: 3.3968x; 3.3968x over previous
//
#include <hip/hip_runtime.h>

#define SS 1024
#define DD 512
#define BATCH 8
#define MIN_T 0.1f
#define MAX_T 0.9f

using half8  = __attribute__((ext_vector_type(8))) _Float16;
using floatx4 = __attribute__((ext_vector_type(4))) float;

typedef const __attribute__((address_space(1))) void gvoid;
typedef __attribute__((address_space(3))) void lvoid;

// ---------------- denominators (read fp32 adj, prune inline) ----------------
__global__ void denom_row_k(const float* __restrict__ adj, float* __restrict__ rden) {
    int row = blockIdx.x;  // b*S + x
    const float* a = adj + (size_t)row * SS;
    float s = 0.f;
    for (int y = threadIdx.x; y < SS; y += blockDim.x) {
        float v = a[y];
        s += (v >= MIN_T && v <= MAX_T) ? v : 0.f;
    }
    __shared__ float red[256];
    red[threadIdx.x] = s;
    __syncthreads();
    for (int off = 128; off > 0; off >>= 1) {
        if (threadIdx.x < off) red[threadIdx.x] += red[threadIdx.x + off];
        __syncthreads();
    }
    if (threadIdx.x == 0) rden[row] = 1.0f / (red[0] + 1.0f);
}

__global__ void denom_col_k(const float* __restrict__ adj, float* __restrict__ rden) {
    int b = blockIdx.y;
    int y = blockIdx.x * 256 + threadIdx.x;
    const float* a = adj + (size_t)b * SS * SS;
    float s = 0.f;
    for (int x = 0; x < SS; ++x) {
        float v = a[(size_t)x * SS + y];
        s += (v >= MIN_T && v <= MAX_T) ? v : 0.f;
    }
    rden[b * SS + y] = 1.0f / (s + 1.0f);
}

// ---------------- generic cast / prune / transpose prep ----------------
// src [srcR][srcC] (row stride sld, batch bS). Optional natural fp16 copy dN,
// optional fp16 transpose dT [dTR][dTC] (zero-filled where source OOB).
template <typename ST, bool PRUNE, bool DON, bool DOT>
__global__ void prep_k(const ST* __restrict__ src, int sld, long bS,
                       _Float16* __restrict__ dN, int ldN, long bN,
                       _Float16* __restrict__ dT, int ldT, long bT,
                       int srcR, int srcC, int dTR, int dTC) {
    __shared__ float lt[64][65];
    src += (size_t)blockIdx.z * bS;
    int c0 = blockIdx.x * 64, r0 = blockIdx.y * 64;
    int tx = threadIdx.x, ty = threadIdx.y;  // 64 x 4
#pragma unroll
    for (int it = 0; it < 16; ++it) {
        int r = r0 + ty + it * 4, c = c0 + tx;
        float v = 0.f;
        if (r < srcR && c < srcC) v = (float)src[(size_t)r * sld + c];
        if (PRUNE) v = (v >= MIN_T && v <= MAX_T) ? v : 0.f;
        if (DON) {
            if (r < srcR && c < srcC)
                dN[(size_t)blockIdx.z * bN + (size_t)r * ldN + c] = (_Float16)v;
        }
        if (DOT) lt[tx][ty + it * 4] = v;
    }
    if (DOT) {
        __syncthreads();
#pragma unroll
        for (int it = 0; it < 16; ++it) {
            int tr = c0 + ty + it * 4, tc = r0 + tx;
            if (tr < dTR && tc < dTC)
                dT[(size_t)blockIdx.z * bT + (size_t)tr * ldT + tc] =
                    (_Float16)lt[ty + it * 4][tx];
        }
    }
}

__global__ void ubias_k(const float* __restrict__ U, float* __restrict__ ub) {
    int n = blockIdx.x * 64 + threadIdx.x;
    if (n < 576) ub[n] = (n < 513) ? U[512 * 513 + n] : 0.f;
}

// ---------------- MFMA GEMM: C = A[M][K] * B[N][K]^T, fp16 in / fp32 acc ----------------
// EPI: 0 = agg+fp32X add (C fp16), 1 = agg+fp16X add (C fp16),
//      2 = wmm relu((acc+bias)*rden) (C fp16), 3 = t1 acc+Ubias[n] (C fp16),
//      4 = score acc+(float)tb[m*e0ld] (C fp32)
constexpr int GBM = 128, GBN = 64, GBK = 64;

template <int EPI>
__global__ __launch_bounds__(256, 3) void gemm_k(
    const _Float16* __restrict__ A, const _Float16* __restrict__ B, void* __restrict__ Cv,
    int M, int N, int K, int lda, int ldb, int ldc,
    long bA, long bB, long bC,
    const void* __restrict__ e0, int e0ld, long bE0, const float* __restrict__ e1) {
    __shared__ _Float16 lA[2][GBM * GBK];  // [128][64], 8x16B chunks/row, source-swizzled
    __shared__ _Float16 lB[2][GBN * GBK];  // [64][64]

    const int z = blockIdx.z;
    A += (size_t)z * bA;
    B += (size_t)z * bB;
    const int m0 = blockIdx.x * GBM, n0 = blockIdx.y * GBN;
    const int tid = threadIdx.x;
    const int lane = tid & 63, wv = tid >> 6;
    const int wr = wv >> 1, wc = wv & 1;  // 2x2 waves, 64x32 per wave

    auto stage = [&](int buf, int kt) {
#pragma unroll
        for (int it = 0; it < 4; ++it) {  // A: 1024 chunks
            int q = it * 256 + tid;
            int r = q >> 3, cp = q & 7, cl = cp ^ (r & 7);
            const _Float16* g = A + (size_t)(m0 + r) * lda + kt + cl * 8;
            __builtin_amdgcn_global_load_lds((gvoid*)g,
                (lvoid*)(&lA[buf][(it * 256 + wv * 64) * 8]), 16, 0, 0);
        }
#pragma unroll
        for (int it = 0; it < 2; ++it) {  // B: 512 chunks
            int q = it * 256 + tid;
            int r = q >> 3, cp = q & 7, cl = cp ^ (r & 7);
            const _Float16* g = B + (size_t)(n0 + r) * ldb + kt + cl * 8;
            __builtin_amdgcn_global_load_lds((gvoid*)g,
                (lvoid*)(&lB[buf][(it * 256 + wv * 64) * 8]), 16, 0, 0);
        }
    };

    floatx4 acc[4][2] = {};

    stage(0, 0);
    asm volatile("s_waitcnt vmcnt(0)");
    __syncthreads();
    int cur = 0;
    for (int kt = 0; kt < K; kt += GBK) {
        int nxt = kt + GBK;
        if (nxt < K) stage(cur ^ 1, nxt);
#pragma unroll
        for (int kk = 0; kk < 2; ++kk) {
            half8 af[4], bf[2];
#pragma unroll
            for (int i = 0; i < 4; ++i) {
                int row = wr * 64 + i * 16 + (lane & 15);
                int cl = kk * 4 + (lane >> 4);
                int cp = cl ^ (row & 7);
                af[i] = *(const half8*)&lA[cur][row * 64 + cp * 8];
            }
#pragma unroll
            for (int j = 0; j < 2; ++j) {
                int row = wc * 32 + j * 16 + (lane & 15);
                int cl = kk * 4 + (lane >> 4);
                int cp = cl ^ (row & 7);
                bf[j] = *(const half8*)&lB[cur][row * 64 + cp * 8];
            }
#pragma unroll
            for (int i = 0; i < 4; ++i)
#pragma unroll
                for (int j = 0; j < 2; ++j)
                    acc[i][j] = __builtin_amdgcn_mfma_f32_16x16x32_f16(af[i], bf[j], acc[i][j], 0, 0, 0);
        }
        if (nxt < K) {
            asm volatile("s_waitcnt vmcnt(0)");
            __syncthreads();
        }
        cur ^= 1;
    }

    // epilogue: C map col=lane&15, row=(lane>>4)*4+r
    const int cm = (lane >> 4) * 4;
    const int cn = lane & 15;
#pragma unroll
    for (int i = 0; i < 4; ++i) {
#pragma unroll
        for (int j = 0; j < 2; ++j) {
#pragma unroll
            for (int r = 0; r < 4; ++r) {
                int m = m0 + wr * 64 + i * 16 + cm + r;
                int n = n0 + wc * 32 + j * 16 + cn;
                float v = acc[i][j][r];
                if constexpr (EPI == 0) {
                    const float* X = (const float*)e0 + (size_t)z * bE0;
                    v += X[(size_t)m * e0ld + n];
                    ((_Float16*)Cv)[(size_t)z * bC + (size_t)m * ldc + n] = (_Float16)v;
                } else if constexpr (EPI == 1) {
                    const _Float16* X = (const _Float16*)e0 + (size_t)z * bE0;
                    v += (float)X[(size_t)m * e0ld + n];
                    ((_Float16*)Cv)[(size_t)z * bC + (size_t)m * ldc + n] = (_Float16)v;
                } else if constexpr (EPI == 2) {
                    v = (v + ((const float*)e0)[n]) * e1[m];
                    v = v > 0.f ? v : 0.f;
                    ((_Float16*)Cv)[(size_t)z * bC + (size_t)m * ldc + n] = (_Float16)v;
                } else if constexpr (EPI == 3) {
                    v += ((const float*)e0)[n];
                    ((_Float16*)Cv)[(size_t)z * bC + (size_t)m * ldc + n] = (_Float16)v;
                } else {
                    const _Float16* tb = (const _Float16*)e0 + (size_t)z * bE0;
                    v += (float)tb[(size_t)m * e0ld];
                    ((float*)Cv)[(size_t)z * bC + (size_t)m * ldc + n] = v;
                }
            }
        }
    }
}

extern "C" void kernel_launch(void* const* d_in, const int* in_sizes, int n_in,
                              void* d_out, int out_size, void* d_ws, size_t ws_size,
                              hipStream_t stream) {
    const float* x0  = (const float*)d_in[0];  // [B,S,D]
    const float* adj = (const float*)d_in[1];  // [B,S,S]
    const float* W1  = (const float*)d_in[2];  // [L,D,D]
    const float* b1  = (const float*)d_in[3];  // [L,D]
    const float* W2  = (const float*)d_in[4];
    const float* b2  = (const float*)d_in[5];
    const float* U   = (const float*)d_in[6];  // [1,513,513]
    float* out = (float*)d_out;

    char* ws = (char*)d_ws;
    const size_t UNIT = (size_t)BATCH * SS * DD * sizeof(_Float16);  // 8 MB
    _Float16* adjH = (_Float16*)(ws);                       // 16 MB: adjP, then adjPT
    _Float16* u0 = (_Float16*)(ws + 2 * UNIT);              // x0hT, later t1h (spans u0+u1)
    _Float16* u1 = (_Float16*)(ws + 3 * UNIT);              // Yh
    _Float16* u2 = (_Float16*)(ws + 4 * UNIT);              // Xh / h2
    _Float16* u3 = (_Float16*)(ws + 5 * UNIT);              // XhT
    _Float16* u4 = (_Float16*)(ws + 6 * UNIT);              // h1
    _Float16* W1T = (_Float16*)(ws + 7 * UNIT);             // 1 MB
    _Float16* W2T = (_Float16*)(ws + 7 * UNIT + 1048576);   // 1 MB
    _Float16* UT  = (_Float16*)(ws + 7 * UNIT + 2097152);   // 576*512*2 = 0.56 MB
    float* Ubias  = (float*)(ws + 7 * UNIT + 2097152 + 589824);
    float* rden1  = (float*)(ws + 7 * UNIT + 2097152 + 589824 + 4096);
    float* rden2  = rden1 + BATCH * SS;
    _Float16* t1h = u0;  // 8192*576 halfs = 9.44 MB, spans u0 + part of u1 (both dead)

    dim3 tb(64, 4);
    // weight / U / x0 preps
    prep_k<float, false, false, true><<<dim3(8, 8, 2), tb, 0, stream>>>(
        W1, DD, (long)DD * DD, nullptr, 0, 0, W1T, DD, (long)DD * DD, DD, DD, DD, DD);
    prep_k<float, false, false, true><<<dim3(8, 8, 2), tb, 0, stream>>>(
        W2, DD, (long)DD * DD, nullptr, 0, 0, W2T, DD, (long)DD * DD, DD, DD, DD, DD);
    prep_k<float, false, false, true><<<dim3(9, 8, 1), tb, 0, stream>>>(
        U, 513, 0, nullptr, 0, 0, UT, DD, 0, 512, 513, 576, 512);
    ubias_k<<<9, 64, 0, stream>>>(U, Ubias);
    prep_k<float, false, false, true><<<dim3(8, 16, BATCH), tb, 0, stream>>>(
        x0, DD, (long)SS * DD, nullptr, 0, 0, u0, SS, (long)SS * DD, SS, DD, DD, SS);
    denom_row_k<<<BATCH * SS, 256, 0, stream>>>(adj, rden1);
    denom_col_k<<<dim3(SS / 256, BATCH), 256, 0, stream>>>(adj, rden2);

    const long bAdj = (long)SS * SS, bAct = (long)SS * DD;
    dim3 gAgg(SS / GBM, DD / GBN, BATCH);        // (8,8,8)
    dim3 gWmm(BATCH * SS / GBM, DD / GBN, 1);    // (64,8)
    dim3 gT1(BATCH * SS / GBM, 576 / GBN, 1);    // (64,9)
    dim3 gSc(SS / GBM, SS / GBN, BATCH);         // (8,16,8)

    for (int st = 0; st < 2; ++st) {
        const _Float16* WT = st == 0 ? W1T : W2T;
        const float* bias = st == 0 ? b1 : b2;
        const float* rden = st == 0 ? rden1 : rden2;
        _Float16* hout = st == 0 ? u4 : u2;
        // adjacency fp16 (stream 0: natural pruned; stream 1: transposed pruned)
        if (st == 0)
            prep_k<float, true, true, false><<<dim3(16, 16, BATCH), tb, 0, stream>>>(
                adj, SS, bAdj, adjH, SS, bAdj, nullptr, 0, 0, SS, SS, SS, SS);
        else
            prep_k<float, true, false, true><<<dim3(16, 16, BATCH), tb, 0, stream>>>(
                adj, SS, bAdj, nullptr, 0, 0, adjH, SS, bAdj, SS, SS, SS, SS);
        // layer 0: Y = A*x0 + x0 (x0 read fp32)
        gemm_k<0><<<gAgg, 256, 0, stream>>>(adjH, u0, u1, SS, DD, SS, SS, SS, DD,
                                            bAdj, bAct, bAct, x0, DD, bAct, nullptr);
        gemm_k<2><<<gWmm, 256, 0, stream>>>(u1, WT, u2, BATCH * SS, DD, DD, DD, DD, DD,
                                            0, 0, 0, bias, 0, 0, rden);
        // transpose activations for next aggregation
        prep_k<_Float16, false, false, true><<<dim3(8, 16, BATCH), tb, 0, stream>>>(
            u2, DD, bAct, nullptr, 0, 0, u3, SS, bAct, SS, DD, DD, SS);
        // layer 1
        gemm_k<1><<<gAgg, 256, 0, stream>>>(adjH, u3, u1, SS, DD, SS, SS, SS, DD,
                                            bAdj, bAct, bAct, u2, DD, bAct, nullptr);
        gemm_k<2><<<gWmm, 256, 0, stream>>>(u1, WT + DD * DD, hout, BATCH * SS, DD, DD, DD, DD, DD,
                                            0, 0, 0, bias + DD, 0, 0, rden);
    }

    // t1 = [h1|1]*U  -> fp16 [8192][576] (col 512 carries the y-side bias term)
    gemm_k<3><<<gT1, 256, 0, stream>>>(u4, UT, t1h, BATCH * SS, 576, DD, DD, DD, 576,
                                       0, 0, 0, Ubias, 0, 0, nullptr);
    // score[b,x,y] = t1[b,x,:512].h2[b,y,:512] + t1[b,x,512]
    gemm_k<4><<<gSc, 256, 0, stream>>>(t1h, u2, out, SS, SS, DD, 576, DD, SS,
                                       (long)SS * 576, bAct, (long)SS * SS,
                                       t1h + 512, 576, (long)SS * 576, nullptr);
}

// Round 3
// 227.196 us; speedup vs baseline: 4.8104x; 1.4162x over previous
//
#include <hip/hip_runtime.h>

#define SS 1024
#define DD 512
#define BATCH 8
#define MIN_T 0.1f
#define MAX_T 0.9f

using half8  = __attribute__((ext_vector_type(8))) _Float16;
using floatx4 = __attribute__((ext_vector_type(4))) float;

typedef const __attribute__((address_space(1))) void gvoid;
typedef __attribute__((address_space(3))) void lvoid;

// ---------------- row-sum of pruned fp16 matrix -> rden = 1/(sum+1) ----------------
// One wave per row of a [rows][1024] fp16 matrix (K-contiguous). Coalesced half8 loads.
__global__ void rsum_k(const _Float16* __restrict__ A, float* __restrict__ rden, int rows) {
    int row = blockIdx.x * 4 + (threadIdx.x >> 6);
    if (row >= rows) return;
    int lane = threadIdx.x & 63;
    const _Float16* a = A + (size_t)row * SS;
    float s = 0.f;
#pragma unroll
    for (int r = 0; r < 2; ++r) {
        half8 v = *(const half8*)&a[(lane + 64 * r) * 8];
#pragma unroll
        for (int j = 0; j < 8; ++j) s += (float)v[j];
    }
#pragma unroll
    for (int m = 32; m > 0; m >>= 1) s += __shfl_xor(s, m, 64);
    if (lane == 0) rden[row] = 1.0f / (s + 1.0f);
}

// ---------------- generic cast / prune / transpose prep ----------------
// src [srcR][srcC] (row stride sld, batch bS). Optional natural fp16 copy dN,
// optional fp16 transpose dT [dTR][dTC] (zero-filled where source OOB).
template <typename ST, bool PRUNE, bool DON, bool DOT>
__global__ void prep_k(const ST* __restrict__ src, int sld, long bS,
                       _Float16* __restrict__ dN, int ldN, long bN,
                       _Float16* __restrict__ dT, int ldT, long bT,
                       int srcR, int srcC, int dTR, int dTC) {
    __shared__ float lt[64][65];
    src += (size_t)blockIdx.z * bS;
    int c0 = blockIdx.x * 64, r0 = blockIdx.y * 64;
    int tx = threadIdx.x, ty = threadIdx.y;  // 64 x 4
#pragma unroll
    for (int it = 0; it < 16; ++it) {
        int r = r0 + ty + it * 4, c = c0 + tx;
        float v = 0.f;
        if (r < srcR && c < srcC) v = (float)src[(size_t)r * sld + c];
        if (PRUNE) v = (v >= MIN_T && v <= MAX_T) ? v : 0.f;
        if (DON) {
            if (r < srcR && c < srcC)
                dN[(size_t)blockIdx.z * bN + (size_t)r * ldN + c] = (_Float16)v;
        }
        if (DOT) lt[tx][ty + it * 4] = v;
    }
    if (DOT) {
        __syncthreads();
#pragma unroll
        for (int it = 0; it < 16; ++it) {
            int tr = c0 + ty + it * 4, tc = r0 + tx;
            if (tr < dTR && tc < dTC)
                dT[(size_t)blockIdx.z * bT + (size_t)tr * ldT + tc] =
                    (_Float16)lt[ty + it * 4][tx];
        }
    }
}

__global__ void ubias_k(const float* __restrict__ U, float* __restrict__ ub) {
    int n = blockIdx.x * 64 + threadIdx.x;
    if (n < 576) ub[n] = (n < 513) ? U[512 * 513 + n] : 0.f;
}

// ---------------- MFMA GEMM: C = A[M][K] * B[N][K]^T, fp16 in / fp32 acc ----------------
// EPI: 0 = agg+fp32X add (C fp16), 1 = agg+fp16X add (C fp16),
//      2 = wmm relu((acc+bias)*rden) (C fp16), 3 = t1 acc+Ubias[n] (C fp16),
//      4 = score acc+(float)tb[m*e0ld] (C fp32)
constexpr int GBM = 128, GBN = 64, GBK = 64;

template <int EPI>
__global__ __launch_bounds__(256, 3) void gemm_k(
    const _Float16* __restrict__ A, const _Float16* __restrict__ B, void* __restrict__ Cv,
    int M, int N, int K, int lda, int ldb, int ldc,
    long bA, long bB, long bC,
    const void* __restrict__ e0, int e0ld, long bE0, const float* __restrict__ e1) {
    __shared__ _Float16 lA[2][GBM * GBK];  // [128][64], 8x16B chunks/row, source-swizzled
    __shared__ _Float16 lB[2][GBN * GBK];  // [64][64]

    const int z = blockIdx.z;
    A += (size_t)z * bA;
    B += (size_t)z * bB;
    const int m0 = blockIdx.x * GBM, n0 = blockIdx.y * GBN;
    const int tid = threadIdx.x;
    const int lane = tid & 63, wv = tid >> 6;
    const int wr = wv >> 1, wc = wv & 1;  // 2x2 waves, 64x32 per wave

    auto stage = [&](int buf, int kt) {
#pragma unroll
        for (int it = 0; it < 4; ++it) {  // A: 1024 chunks
            int q = it * 256 + tid;
            int r = q >> 3, cp = q & 7, cl = cp ^ (r & 7);
            const _Float16* g = A + (size_t)(m0 + r) * lda + kt + cl * 8;
            __builtin_amdgcn_global_load_lds((gvoid*)g,
                (lvoid*)(&lA[buf][(it * 256 + wv * 64) * 8]), 16, 0, 0);
        }
#pragma unroll
        for (int it = 0; it < 2; ++it) {  // B: 512 chunks
            int q = it * 256 + tid;
            int r = q >> 3, cp = q & 7, cl = cp ^ (r & 7);
            const _Float16* g = B + (size_t)(n0 + r) * ldb + kt + cl * 8;
            __builtin_amdgcn_global_load_lds((gvoid*)g,
                (lvoid*)(&lB[buf][(it * 256 + wv * 64) * 8]), 16, 0, 0);
        }
    };

    floatx4 acc[4][2] = {};

    stage(0, 0);
    asm volatile("s_waitcnt vmcnt(0)");
    __syncthreads();
    int cur = 0;
    for (int kt = 0; kt < K; kt += GBK) {
        int nxt = kt + GBK;
        if (nxt < K) stage(cur ^ 1, nxt);
#pragma unroll
        for (int kk = 0; kk < 2; ++kk) {
            half8 af[4], bf[2];
#pragma unroll
            for (int i = 0; i < 4; ++i) {
                int row = wr * 64 + i * 16 + (lane & 15);
                int cl = kk * 4 + (lane >> 4);
                int cp = cl ^ (row & 7);
                af[i] = *(const half8*)&lA[cur][row * 64 + cp * 8];
            }
#pragma unroll
            for (int j = 0; j < 2; ++j) {
                int row = wc * 32 + j * 16 + (lane & 15);
                int cl = kk * 4 + (lane >> 4);
                int cp = cl ^ (row & 7);
                bf[j] = *(const half8*)&lB[cur][row * 64 + cp * 8];
            }
#pragma unroll
            for (int i = 0; i < 4; ++i)
#pragma unroll
                for (int j = 0; j < 2; ++j)
                    acc[i][j] = __builtin_amdgcn_mfma_f32_16x16x32_f16(af[i], bf[j], acc[i][j], 0, 0, 0);
        }
        if (nxt < K) {
            asm volatile("s_waitcnt vmcnt(0)");
            __syncthreads();
        }
        cur ^= 1;
    }

    // epilogue: C map col=lane&15, row=(lane>>4)*4+r
    const int cm = (lane >> 4) * 4;
    const int cn = lane & 15;
#pragma unroll
    for (int i = 0; i < 4; ++i) {
#pragma unroll
        for (int j = 0; j < 2; ++j) {
#pragma unroll
            for (int r = 0; r < 4; ++r) {
                int m = m0 + wr * 64 + i * 16 + cm + r;
                int n = n0 + wc * 32 + j * 16 + cn;
                float v = acc[i][j][r];
                if constexpr (EPI == 0) {
                    const float* X = (const float*)e0 + (size_t)z * bE0;
                    v += X[(size_t)m * e0ld + n];
                    ((_Float16*)Cv)[(size_t)z * bC + (size_t)m * ldc + n] = (_Float16)v;
                } else if constexpr (EPI == 1) {
                    const _Float16* X = (const _Float16*)e0 + (size_t)z * bE0;
                    v += (float)X[(size_t)m * e0ld + n];
                    ((_Float16*)Cv)[(size_t)z * bC + (size_t)m * ldc + n] = (_Float16)v;
                } else if constexpr (EPI == 2) {
                    v = (v + ((const float*)e0)[n]) * e1[m];
                    v = v > 0.f ? v : 0.f;
                    ((_Float16*)Cv)[(size_t)z * bC + (size_t)m * ldc + n] = (_Float16)v;
                } else if constexpr (EPI == 3) {
                    v += ((const float*)e0)[n];
                    ((_Float16*)Cv)[(size_t)z * bC + (size_t)m * ldc + n] = (_Float16)v;
                } else {
                    const _Float16* tb = (const _Float16*)e0 + (size_t)z * bE0;
                    v += (float)tb[(size_t)m * e0ld];
                    ((float*)Cv)[(size_t)z * bC + (size_t)m * ldc + n] = v;
                }
            }
        }
    }
}

extern "C" void kernel_launch(void* const* d_in, const int* in_sizes, int n_in,
                              void* d_out, int out_size, void* d_ws, size_t ws_size,
                              hipStream_t stream) {
    const float* x0  = (const float*)d_in[0];  // [B,S,D]
    const float* adj = (const float*)d_in[1];  // [B,S,S]
    const float* W1  = (const float*)d_in[2];  // [L,D,D]
    const float* b1  = (const float*)d_in[3];  // [L,D]
    const float* W2  = (const float*)d_in[4];
    const float* b2  = (const float*)d_in[5];
    const float* U   = (const float*)d_in[6];  // [1,513,513]
    float* out = (float*)d_out;

    char* ws = (char*)d_ws;
    const size_t UNIT = (size_t)BATCH * SS * DD * sizeof(_Float16);  // 8 MB
    _Float16* adjH = (_Float16*)(ws);                       // 16 MB: adjP, then adjPT
    _Float16* u0 = (_Float16*)(ws + 2 * UNIT);              // x0hT, later t1h (spans u0+u1)
    _Float16* u1 = (_Float16*)(ws + 3 * UNIT);              // Yh
    _Float16* u2 = (_Float16*)(ws + 4 * UNIT);              // Xh / h2
    _Float16* u3 = (_Float16*)(ws + 5 * UNIT);              // XhT
    _Float16* u4 = (_Float16*)(ws + 6 * UNIT);              // h1
    _Float16* W1T = (_Float16*)(ws + 7 * UNIT);             // 1 MB
    _Float16* W2T = (_Float16*)(ws + 7 * UNIT + 1048576);   // 1 MB
    _Float16* UT  = (_Float16*)(ws + 7 * UNIT + 2097152);   // 576*512*2 = 0.56 MB
    float* Ubias  = (float*)(ws + 7 * UNIT + 2097152 + 589824);
    float* rden1  = (float*)(ws + 7 * UNIT + 2097152 + 589824 + 4096);
    float* rden2  = rden1 + BATCH * SS;
    _Float16* t1h = u0;  // 8192*576 halfs = 9.44 MB, spans u0 + part of u1 (both dead)

    dim3 tb(64, 4);
    // weight / U / x0 preps
    prep_k<float, false, false, true><<<dim3(8, 8, 2), tb, 0, stream>>>(
        W1, DD, (long)DD * DD, nullptr, 0, 0, W1T, DD, (long)DD * DD, DD, DD, DD, DD);
    prep_k<float, false, false, true><<<dim3(8, 8, 2), tb, 0, stream>>>(
        W2, DD, (long)DD * DD, nullptr, 0, 0, W2T, DD, (long)DD * DD, DD, DD, DD, DD);
    prep_k<float, false, false, true><<<dim3(9, 8, 1), tb, 0, stream>>>(
        U, 513, 0, nullptr, 0, 0, UT, DD, 0, 512, 513, 576, 512);
    ubias_k<<<9, 64, 0, stream>>>(U, Ubias);
    prep_k<float, false, false, true><<<dim3(8, 16, BATCH), tb, 0, stream>>>(
        x0, DD, (long)SS * DD, nullptr, 0, 0, u0, SS, (long)SS * DD, SS, DD, DD, SS);

    const long bAdj = (long)SS * SS, bAct = (long)SS * DD;
    dim3 gAgg(SS / GBM, DD / GBN, BATCH);        // (8,8,8)
    dim3 gWmm(BATCH * SS / GBM, DD / GBN, 1);    // (64,8)
    dim3 gT1(BATCH * SS / GBM, 576 / GBN, 1);    // (64,9)
    dim3 gSc(SS / GBM, SS / GBN, BATCH);         // (8,16,8)

    for (int st = 0; st < 2; ++st) {
        const _Float16* WT = st == 0 ? W1T : W2T;
        const float* bias = st == 0 ? b1 : b2;
        const float* rden = st == 0 ? rden1 : rden2;
        _Float16* hout = st == 0 ? u4 : u2;
        // adjacency fp16 (stream 0: natural pruned; stream 1: transposed pruned)
        if (st == 0)
            prep_k<float, true, true, false><<<dim3(16, 16, BATCH), tb, 0, stream>>>(
                adj, SS, bAdj, adjH, SS, bAdj, nullptr, 0, 0, SS, SS, SS, SS);
        else
            prep_k<float, true, false, true><<<dim3(16, 16, BATCH), tb, 0, stream>>>(
                adj, SS, bAdj, nullptr, 0, 0, adjH, SS, bAdj, SS, SS, SS, SS);
        // denominators from the pruned fp16 adjacency (coalesced row-sums):
        // st=0: row-sums of adj -> rden1; st=1: row-sums of adj^T (= col-sums) -> rden2
        rsum_k<<<BATCH * SS / 4, 256, 0, stream>>>(adjH, st == 0 ? rden1 : rden2, BATCH * SS);
        // layer 0: Y = A*x0 + x0 (x0 read fp32)
        gemm_k<0><<<gAgg, 256, 0, stream>>>(adjH, u0, u1, SS, DD, SS, SS, SS, DD,
                                            bAdj, bAct, bAct, x0, DD, bAct, nullptr);
        gemm_k<2><<<gWmm, 256, 0, stream>>>(u1, WT, u2, BATCH * SS, DD, DD, DD, DD, DD,
                                            0, 0, 0, bias, 0, 0, rden);
        // transpose activations for next aggregation
        prep_k<_Float16, false, false, true><<<dim3(8, 16, BATCH), tb, 0, stream>>>(
            u2, DD, bAct, nullptr, 0, 0, u3, SS, bAct, SS, DD, DD, SS);
        // layer 1
        gemm_k<1><<<gAgg, 256, 0, stream>>>(adjH, u3, u1, SS, DD, SS, SS, SS, DD,
                                            bAdj, bAct, bAct, u2, DD, bAct, nullptr);
        gemm_k<2><<<gWmm, 256, 0, stream>>>(u1, WT + DD * DD, hout, BATCH * SS, DD, DD, DD, DD, DD,
                                            0, 0, 0, bias + DD, 0, 0, rden);
    }

    // t1 = [h1|1]*U  -> fp16 [8192][576] (col 512 carries the y-side bias term)
    gemm_k<3><<<gT1, 256, 0, stream>>>(u4, UT, t1h, BATCH * SS, 576, DD, DD, DD, 576,
                                       0, 0, 0, Ubias, 0, 0, nullptr);
    // score[b,x,y] = t1[b,x,:512].h2[b,y,:512] + t1[b,x,512]
    gemm_k<4><<<gSc, 256, 0, stream>>>(t1h, u2, out, SS, SS, DD, 576, DD, SS,
                                       (long)SS * 576, bAct, (long)SS * SS,
                                       t1h + 512, 576, (long)SS * 576, nullptr);
}